// Round 5
// baseline (348.629 us; speedup 1.0000x reference)
//
#include <hip/hip_runtime.h>
#include <stdint.h>
#include <math.h>

#define NEGV -1000000000.0f

constexpr int NG   = 256;   // graphs
constexpr int NL   = 32;    // nodes per graph == L == steps
constexpr int NT   = 1024;  // threads per block
constexpr int NTOT = 8192;  // total nodes
constexpr int S3   = 33;    // stride for per-lane-row-read arrays
constexpr int S4   = 34;    // stride for broadcast-read arrays (float2-aligned)

typedef __attribute__((ext_vector_type(8))) short bf16x8;
typedef __attribute__((ext_vector_type(4))) float f32x4;
typedef __attribute__((ext_vector_type(2))) float f32x2;

__device__ __forceinline__ float lrelu(float v) { return fmaxf(v, 0.01f * v); }

__device__ __forceinline__ uint32_t pack_bf2_rne(float a, float b) {
  uint32_t ua = __float_as_uint(a); ua = (ua + 0x7fffu + ((ua >> 16) & 1u)) >> 16;
  uint32_t ub = __float_as_uint(b); ub = (ub + 0x7fffu + ((ub >> 16) & 1u)) >> 16;
  return ua | (ub << 16);
}
// pack truncated-bf16 of lo,hi into one u32: low16 = lo>>16, high16 = hi&ffff0000
__device__ __forceinline__ uint32_t pack_tr(float lo, float hi) {
  return __builtin_amdgcn_perm(__float_as_uint(hi), __float_as_uint(lo), 0x07060302u);
}

__device__ __forceinline__ void lds_barrier() {
  asm volatile("s_waitcnt lgkmcnt(0)" ::: "memory");
  __builtin_amdgcn_sched_barrier(0);
  __builtin_amdgcn_s_barrier();
  __builtin_amdgcn_sched_barrier(0);
}

__device__ __forceinline__ float fsigmoid(float x) {
  return __builtin_amdgcn_rcpf(1.f + __expf(-x));
}
__device__ __forceinline__ float ftanh(float x) {
  x = fminf(fmaxf(x, -15.f), 15.f);
  float e = __expf(2.f * x);
  return (e - 1.f) * __builtin_amdgcn_rcpf(e + 1.f);
}

__global__ __launch_bounds__(NT, 4) void prims_fused(
    const float* __restrict__ x, const float* __restrict__ edge_attr,
    const float* __restrict__ W_enc, const float* __restrict__ W_m1,
    const float* __restrict__ W_m2, const float* __restrict__ W_u,
    const float* __restrict__ W_ih, const float* __restrict__ W_hh,
    const float* __restrict__ W_mst, const float* __restrict__ W_p1,
    const float* __restrict__ W_p2, float* __restrict__ out)
{
  __shared__ __align__(16) float sh[NL * S4];     // hidden state h (broadcast reads)
  __shared__ __align__(16) float senc[NL * S4];   // enc
  __shared__ __align__(16) float sA[NL * S4];     // msg dst-part; then u; then C1
  __shared__ __align__(16) float saggr[NL * S4];  // segment max
  __shared__ float sB[NL * S3];                   // msg src-part; then C2
  __shared__ float sea[NL * S3];                  // sea[j*S3 + i] = ea(src i, dst j)
  __shared__ __align__(8) float swea[NL];         // W_m1[:,64]; later W_p1[:,64]
  __shared__ float smst[NL];
  __shared__ float swenc0[NL];
  __shared__ float sWmst[2 * NL];
  __shared__ f32x2 sWenc2[NL * 17];   // W_enc[:,1:33] pairs
  __shared__ f32x2 sW1d2[NL * 17];    // W_m1[:, 0:32] pairs
  __shared__ f32x2 sW1s2[NL * 17];    // W_m1[:,32:64] pairs
  __shared__ f32x2 sWu2[NL * 33];     // W_u pairs
  __shared__ f32x2 sWihF[96 * 17];    // W_ih f32 pairs
  __shared__ f32x2 sWhhF[96 * 17];    // W_hh f32 pairs

  const int t    = threadIdx.x;
  const int g    = blockIdx.x;
  const int p    = t >> 5;   // node row
  const int k    = t & 31;   // feature col
  const int w    = t >> 6;   // wave id (16)
  const int lane = t & 63;
  const int l32  = lane & 31;
  const int m16  = lane & 15;
  const int c0   = (lane >> 4) * 8;  // MFMA k-chunk base

  // ---- W_m2^T B-fragments, resident in registers ----
  bf16x8 bf0, bf1;
  {
    union { uint32_t u[4]; bf16x8 v; } p0, p1;
    #pragma unroll
    for (int q = 0; q < 4; ++q) {
      p0.u[q] = pack_bf2_rne(W_m2[m16 * 32 + c0 + 2 * q], W_m2[m16 * 32 + c0 + 2 * q + 1]);
      p1.u[q] = pack_bf2_rne(W_m2[(16 + m16) * 32 + c0 + 2 * q], W_m2[(16 + m16) * 32 + c0 + 2 * q + 1]);
    }
    bf0 = p0.v; bf1 = p1.v;
  }

  // ---- one-time staging ----
  for (int idx = t; idx < NL * 16; idx += NT) {
    int r = idx >> 4, c2 = idx & 15;
    sWenc2[r * 17 + c2] = (f32x2){W_enc[r * 33 + 1 + 2 * c2], W_enc[r * 33 + 2 + 2 * c2]};
    sW1d2[r * 17 + c2] = (f32x2){W_m1[r * 65 + 2 * c2],      W_m1[r * 65 + 2 * c2 + 1]};
    sW1s2[r * 17 + c2] = (f32x2){W_m1[r * 65 + 32 + 2 * c2], W_m1[r * 65 + 33 + 2 * c2]};
  }
  for (int idx = t; idx < NL * 32; idx += NT) {
    int r = idx >> 5, c2 = idx & 31;
    sWu2[r * 33 + c2] = (f32x2){W_u[r * 64 + 2 * c2], W_u[r * 64 + 2 * c2 + 1]};
  }
  for (int idx = t; idx < 96 * 16; idx += NT) {
    int q = idx >> 4, c2 = idx & 15;
    sWihF[q * 17 + c2] = (f32x2){W_ih[q * 32 + 2 * c2], W_ih[q * 32 + 2 * c2 + 1]};
    sWhhF[q * 17 + c2] = (f32x2){W_hh[q * 32 + 2 * c2], W_hh[q * 32 + 2 * c2 + 1]};
  }
  if (t < NL) { swenc0[t] = W_enc[t * 33]; swea[t] = W_m1[t * 65 + 64]; }
  if (t < 2 * NL) sWmst[t] = W_mst[t];
  {
    int i = t >> 5, j = t & 31;            // edge t = i*32+j
    sea[j * S3 + i] = edge_attr[g * 1024 + t];
  }
  for (int idx = t; idx < NL * S4; idx += NT) sh[idx] = 0.f;

  // per-lane register copies of prev (no LDS for prev at all)
  float prev_row  = x[(size_t)(g * NL + p)   * 32];  // prev[p], for enc
  float prev_lane = x[(size_t)(g * NL + l32) * 32];  // prev[l32], for argmax
  float h_reg = 0.f;                                  // h[p][k], own element

  __syncthreads();

  // ---- 32 steps ----
  for (int s = 0; s < 32; ++s) {
    // NEG-fill slice of this graph's band (skips diagonal block; overlaps compute)
    {
      const f32x4 nv = {NEGV, NEGV, NEGV, NEGV};
      #pragma unroll
      for (int q = 0; q < 2; ++q) {
        int idx = (s * 2 + q) * NT + t;
        int row = idx >> 11;
        int c4  = idx & 2047;
        if ((c4 >> 3) != g) {
          f32x4* dptr = reinterpret_cast<f32x4*>(out + (size_t)(g * NL + row) * NTOT) + c4;
          __builtin_nontemporal_store(nv, dptr);
        }
      }
    }

    // enc = relu([prev | h] @ W_enc.T)   (own rows)
    float enc_reg;
    {
      const f32x2* h2 = (const f32x2*)&sh[p * S4];
      f32x2 accA = {0.f, 0.f}, accB = {0.f, 0.f};
      #pragma unroll
      for (int c2 = 0; c2 < 16; c2 += 2) {
        accA = __builtin_elementwise_fma(sWenc2[k * 17 + c2],     h2[c2],     accA);
        accB = __builtin_elementwise_fma(sWenc2[k * 17 + c2 + 1], h2[c2 + 1], accB);
      }
      float acc = fmaf(swenc0[k], prev_row, (accA.x + accA.y) + (accB.x + accB.y));
      enc_reg = fmaxf(acc, 0.f);
      senc[p * S4 + k] = enc_reg;
    }

    // A/B = enc @ W_m1 halves  (own rows)
    {
      const f32x2* e2 = (const f32x2*)&senc[p * S4];
      f32x2 a2 = {0.f, 0.f}, b2 = {0.f, 0.f};
      #pragma unroll
      for (int c2 = 0; c2 < 16; ++c2) {
        f32x2 ev = e2[c2];
        a2 = __builtin_elementwise_fma(sW1d2[k * 17 + c2], ev, a2);
        b2 = __builtin_elementwise_fma(sW1s2[k * 17 + c2], ev, b2);
      }
      sA[p * S4 + k] = a2.x + a2.y;
      sB[p * S3 + k] = b2.x + b2.y;
    }
    lds_barrier();   // B1: sA/sB all rows visible

    // edge phase via MFMA: wave w owns dst j = 2w, 2w+1
    {
      const f32x2* wv2 = (const f32x2*)&swea[c0];
      float wv[8];
      #pragma unroll
      for (int q = 0; q < 4; ++q) { f32x2 v = wv2[q]; wv[2*q] = v.x; wv[2*q+1] = v.y; }
      const f32x4 zero = {0.f, 0.f, 0.f, 0.f};
      #pragma unroll
      for (int jg = 0; jg < 2; ++jg) {
        const int j = 2 * w + jg;
        const f32x2* aj2 = (const f32x2*)&sA[j * S4 + c0];
        float Aj[8];
        #pragma unroll
        for (int q = 0; q < 4; ++q) { f32x2 v = aj2[q]; Aj[2*q] = v.x; Aj[2*q+1] = v.y; }
        const float ea0 = sea[j * S3 + m16];
        const float ea1 = sea[j * S3 + 16 + m16];
        const float* b0 = &sB[m16 * S3 + c0];
        const float* b1 = &sB[(16 + m16) * S3 + c0];
        union { uint32_t u[4]; bf16x8 v; } a0, a1;
        #pragma unroll
        for (int q = 0; q < 4; ++q) {
          float v00 = lrelu(Aj[2*q]   + fmaf(ea0, wv[2*q],   b0[2*q]));
          float v01 = lrelu(Aj[2*q+1] + fmaf(ea0, wv[2*q+1], b0[2*q+1]));
          float v10 = lrelu(Aj[2*q]   + fmaf(ea1, wv[2*q],   b1[2*q]));
          float v11 = lrelu(Aj[2*q+1] + fmaf(ea1, wv[2*q+1], b1[2*q+1]));
          a0.u[q] = pack_tr(v00, v01);
          a1.u[q] = pack_tr(v10, v11);
        }
        f32x4 d00 = __builtin_amdgcn_mfma_f32_16x16x32_bf16(a0.v, bf0, zero, 0, 0, 0);
        f32x4 d01 = __builtin_amdgcn_mfma_f32_16x16x32_bf16(a0.v, bf1, zero, 0, 0, 0);
        f32x4 d10 = __builtin_amdgcn_mfma_f32_16x16x32_bf16(a1.v, bf0, zero, 0, 0, 0);
        f32x4 d11 = __builtin_amdgcn_mfma_f32_16x16x32_bf16(a1.v, bf1, zero, 0, 0, 0);
        #pragma unroll
        for (int nt = 0; nt < 2; ++nt) {
          f32x4 da = nt ? d01 : d00;
          f32x4 db = nt ? d11 : d10;
          // max over raw values; lrelu is monotone -> apply once at the end
          float mv = fmaxf(fmaxf(fmaxf(da[0], da[1]), fmaxf(da[2], da[3])),
                           fmaxf(fmaxf(db[0], db[1]), fmaxf(db[2], db[3])));
          mv = fmaxf(mv, __shfl_xor(mv, 16));
          mv = fmaxf(mv, __shfl_xor(mv, 32));
          if (lane < 16) saggr[j * S4 + nt * 16 + lane] = lrelu(mv);
        }
      }
    }

    // u = lrelu([enc | aggr] @ W_u.T) -> sA (own rows)
    {
      const f32x2* e2 = (const f32x2*)&senc[p * S4];
      const f32x2* g2 = (const f32x2*)&saggr[p * S4];
      f32x2 accA = {0.f, 0.f}, accB = {0.f, 0.f};
      #pragma unroll
      for (int c2 = 0; c2 < 16; ++c2)
        accA = __builtin_elementwise_fma(sWu2[k * 33 + c2], e2[c2], accA);
      #pragma unroll
      for (int c2 = 0; c2 < 16; ++c2)
        accB = __builtin_elementwise_fma(sWu2[k * 33 + 16 + c2], g2[c2], accB);
      float ur = (accA.x + accA.y) + (accB.x + accB.y);
      sA[p * S4 + k] = lrelu(ur);
    }

    // GRU (own rows) — all-f32 weights, h_old from register
    float hnew;
    {
      const f32x2* u2 = (const f32x2*)&sA[p * S4];
      const f32x2* h2 = (const f32x2*)&sh[p * S4];
      f32x2 gr = {0,0}, gz = {0,0}, gn = {0,0}, hr = {0,0}, hz = {0,0}, hn = {0,0};
      #pragma unroll
      for (int c2 = 0; c2 < 16; ++c2) {
        f32x2 uu = u2[c2], hh = h2[c2];
        gr = __builtin_elementwise_fma(sWihF[k * 17 + c2],        uu, gr);
        gz = __builtin_elementwise_fma(sWihF[(32 + k) * 17 + c2], uu, gz);
        gn = __builtin_elementwise_fma(sWihF[(64 + k) * 17 + c2], uu, gn);
        hr = __builtin_elementwise_fma(sWhhF[k * 17 + c2],        hh, hr);
        hz = __builtin_elementwise_fma(sWhhF[(32 + k) * 17 + c2], hh, hz);
        hn = __builtin_elementwise_fma(sWhhF[(64 + k) * 17 + c2], hh, hn);
      }
      float r  = fsigmoid((gr.x + gr.y) + (hr.x + hr.y));
      float z  = fsigmoid((gz.x + gz.y) + (hz.x + hz.y));
      float nn = ftanh((gn.x + gn.y) + r * (hn.x + hn.y));
      hnew = (1.f - z) * nn + z * h_reg;
    }
    h_reg = hnew;
    sh[p * S4 + k] = hnew;

    // mst partial from registers (no LDS round-trip on the critical path)
    {
      float part = sWmst[k] * enc_reg + sWmst[32 + k] * hnew;
      #pragma unroll
      for (int mask = 1; mask <= 16; mask <<= 1) part += __shfl_xor(part, mask);
      if (k == 0) smst[p] = part;
    }
    lds_barrier();   // B2: smst all rows visible

    // masked argmax — every wave computes redundantly (identical result);
    // prev kept in per-lane registers, updated from broadcast winner idx
    {
      float val = (prev_lane > 0.f) ? NEGV : smst[l32];
      int idx = l32;
      #pragma unroll
      for (int mask = 16; mask >= 1; mask >>= 1) {
        float ov = __shfl_xor(val, mask);
        int   oi = __shfl_xor(idx, mask);
        if (ov > val || (ov == val && oi < idx)) { val = ov; idx = oi; }
      }
      if (l32 == idx) prev_lane = 1.0f;
      if (p   == idx) prev_row  = 1.0f;
    }
  }

  // ---- final predictor ----
  {
    float c1 = 0.f, c2 = 0.f;
    #pragma unroll
    for (int c = 0; c < 32; ++c) {
      float hc = sh[p * S4 + c];
      c1 = fmaf(W_p1[k * 65 + c],      hc, c1);
      c2 = fmaf(W_p1[k * 65 + 32 + c], hc, c2);
    }
    sA[p * S4 + k] = c1;
    sB[p * S3 + k] = c2;
  }
  if (t < 32) swea[t] = W_p1[t * 65 + 64];
  lds_barrier();

  // out(src=i, dst=j): i = p, j = k
  {
    const int i = p, j = k;
    float eat = sea[j * S3 + i];
    float acc = 0.f;
    #pragma unroll
    for (int c = 0; c < 32; ++c) {
      float v = sA[i * S4 + c] + sB[j * S3 + c] + eat * swea[c];
      acc = fmaf(W_p2[c], fmaxf(v, 0.f), acc);
    }
    out[(size_t)(g * NL + i) * NTOT + (g * NL + j)] = acc;
  }
}

extern "C" void kernel_launch(void* const* d_in, const int* in_sizes, int n_in,
                              void* d_out, int out_size, void* d_ws, size_t ws_size,
                              hipStream_t stream) {
  const float* x         = (const float*)d_in[0];
  const float* edge_attr = (const float*)d_in[1];
  const float* W_enc     = (const float*)d_in[2];
  const float* W_m1      = (const float*)d_in[3];
  const float* W_m2      = (const float*)d_in[4];
  const float* W_u       = (const float*)d_in[5];
  const float* W_ih      = (const float*)d_in[6];
  const float* W_hh      = (const float*)d_in[7];
  const float* W_mst     = (const float*)d_in[8];
  const float* W_p1      = (const float*)d_in[9];
  const float* W_p2      = (const float*)d_in[10];
  float* out = (float*)d_out;

  hipLaunchKernelGGL(prims_fused, dim3(NG), dim3(NT), 0, stream,
                     x, edge_attr, W_enc, W_m1, W_m2, W_u, W_ih, W_hh,
                     W_mst, W_p1, W_p2, out);
}

// Round 7
// 229.568 us; speedup vs baseline: 1.5186x; 1.5186x over previous
//
#include <hip/hip_runtime.h>
#include <stdint.h>
#include <math.h>

#define NEGV -1000000000.0f

constexpr int NG   = 256;   // graphs
constexpr int NL   = 32;    // nodes per graph == L == steps
constexpr int NT   = 1024;  // threads per block
constexpr int NTOT = 8192;  // total nodes
constexpr int S3   = 33;    // f32 stride for per-lane-row arrays
constexpr int SH   = 17;    // half2 stride (34 f16) for packed arrays

typedef _Float16 f16;
typedef __attribute__((ext_vector_type(2))) _Float16 h2;
typedef __attribute__((ext_vector_type(8))) _Float16 f16x8;
typedef __attribute__((ext_vector_type(4))) float f32x4;

#if __has_builtin(__builtin_amdgcn_fdot2)
#define FDOT2(a, b, c) __builtin_amdgcn_fdot2((a), (b), (c), false)
#else
__device__ __forceinline__ float FDOT2(h2 a, h2 b, float c) {
  return fmaf((float)a.y, (float)b.y, fmaf((float)a.x, (float)b.x, c));
}
#endif

#if __has_builtin(__builtin_amdgcn_cvt_pkrtz)
__device__ __forceinline__ h2 PKRTZ(float a, float b) {
  return __builtin_bit_cast(h2, __builtin_amdgcn_cvt_pkrtz(a, b));
}
#else
__device__ __forceinline__ h2 PKRTZ(float a, float b) {
  return (h2){(_Float16)a, (_Float16)b};
}
#endif

__device__ __forceinline__ h2 mkh2(float a, float b) {   // RNE pack (staging only)
  return (h2){(_Float16)a, (_Float16)b};
}

__device__ __forceinline__ float lrelu(float v) { return fmaxf(v, 0.01f * v); }

__device__ __forceinline__ void lds_barrier() {
  asm volatile("s_waitcnt lgkmcnt(0)" ::: "memory");
  __builtin_amdgcn_sched_barrier(0);
  __builtin_amdgcn_s_barrier();
  __builtin_amdgcn_sched_barrier(0);
}

__device__ __forceinline__ float fsigmoid(float x) {
  return __builtin_amdgcn_rcpf(1.f + __expf(-x));
}
__device__ __forceinline__ float ftanh(float x) {
  x = fminf(fmaxf(x, -15.f), 15.f);
  float e = __expf(2.f * x);
  return (e - 1.f) * __builtin_amdgcn_rcpf(e + 1.f);
}

__global__ __launch_bounds__(NT, 4) void prims_fused(
    const float* __restrict__ x, const float* __restrict__ edge_attr,
    const float* __restrict__ W_enc, const float* __restrict__ W_m1,
    const float* __restrict__ W_m2, const float* __restrict__ W_u,
    const float* __restrict__ W_ih, const float* __restrict__ W_hh,
    const float* __restrict__ W_mst, const float* __restrict__ W_p1,
    const float* __restrict__ W_p2, float* __restrict__ out)
{
  // packed f16x2 state (stride 17 half2 = 34 f16)
  __shared__ h2 sh16[NL * SH];     // hidden state h
  __shared__ h2 senc16[NL * SH];   // enc
  __shared__ h2 sA16[NL * SH];     // msg dst-part; then u
  __shared__ h2 sB16[NL * SH];     // msg src-part
  __shared__ h2 saggr16[NL * SH];  // segment max (written as f16 scalars)
  // packed f16x2 weights
  __shared__ h2 sWenc16[NL * SH];  // W_enc[:,1:33]
  __shared__ h2 sW1d16[NL * SH];   // W_m1[:, 0:32]
  __shared__ h2 sW1s16[NL * SH];   // W_m1[:,32:64]
  __shared__ h2 sWu16[NL * 33];    // W_u (64 cols = 32 pairs, pad 1)
  __shared__ h2 sWih16[96 * SH];   // W_ih
  __shared__ h2 sWhh16[96 * SH];   // W_hh
  __shared__ h2 swea16[16];        // W_m1[:,64] pairs
  // f32 oddments
  __shared__ float sea[NL * S3];   // sea[j*S3 + i] = ea(src i, dst j)
  __shared__ float smst[NL];
  __shared__ float swenc0[NL];
  __shared__ float sWmst[2 * NL];
  __shared__ float swp1e[NL];      // W_p1[:,64]
  __shared__ float sC1[NL * S3];   // final predictor src-part
  __shared__ float sC2[NL * S3];   // final predictor dst-part

  const int t    = threadIdx.x;
  const int g    = blockIdx.x;
  const int p    = t >> 5;   // node row
  const int k    = t & 31;   // feature col
  const int w    = t >> 6;   // wave id (16)
  const int lane = t & 63;
  const int l32  = lane & 31;
  const int m16  = lane & 15;
  const int c0   = (lane >> 4) * 8;   // MFMA k-chunk base (f16 elems)
  const int cp0  = (lane >> 4) * 4;   // same in half2 units

  // ---- W_m2^T B-fragments (f16, resident in registers) ----
  union F8 { h2 h[4]; f16x8 v; };
  F8 bf0, bf1;
  #pragma unroll
  for (int q = 0; q < 4; ++q) {
    bf0.h[q] = mkh2(W_m2[m16 * 32 + c0 + 2 * q],        W_m2[m16 * 32 + c0 + 2 * q + 1]);
    bf1.h[q] = mkh2(W_m2[(16 + m16) * 32 + c0 + 2 * q], W_m2[(16 + m16) * 32 + c0 + 2 * q + 1]);
  }

  // ---- one-time staging ----
  for (int idx = t; idx < NL * 16; idx += NT) {
    int r = idx >> 4, c2 = idx & 15;
    sWenc16[r * SH + c2] = mkh2(W_enc[r * 33 + 1 + 2 * c2], W_enc[r * 33 + 2 + 2 * c2]);
    sW1d16[r * SH + c2] = mkh2(W_m1[r * 65 + 2 * c2],      W_m1[r * 65 + 2 * c2 + 1]);
    sW1s16[r * SH + c2] = mkh2(W_m1[r * 65 + 32 + 2 * c2], W_m1[r * 65 + 33 + 2 * c2]);
  }
  for (int idx = t; idx < NL * 32; idx += NT) {
    int r = idx >> 5, c2 = idx & 31;
    sWu16[r * 33 + c2] = mkh2(W_u[r * 64 + 2 * c2], W_u[r * 64 + 2 * c2 + 1]);
  }
  for (int idx = t; idx < 96 * 16; idx += NT) {
    int q = idx >> 4, c2 = idx & 15;
    sWih16[q * SH + c2] = mkh2(W_ih[q * 32 + 2 * c2], W_ih[q * 32 + 2 * c2 + 1]);
    sWhh16[q * SH + c2] = mkh2(W_hh[q * 32 + 2 * c2], W_hh[q * 32 + 2 * c2 + 1]);
  }
  if (t < 16) swea16[t] = mkh2(W_m1[(2 * t) * 65 + 64], W_m1[(2 * t + 1) * 65 + 64]);
  if (t < NL) { swenc0[t] = W_enc[t * 33]; swp1e[t] = W_p1[t * 65 + 64]; }
  if (t < 2 * NL) sWmst[t] = W_mst[t];
  {
    int i = t >> 5, j = t & 31;           // edge t = i*32+j (src i, dst j)
    sea[j * S3 + i] = edge_attr[g * 1024 + t];
  }
  for (int idx = t; idx < NL * SH; idx += NT) sh16[idx] = (h2){(_Float16)0.f, (_Float16)0.f};

  float prev_row  = x[(size_t)(g * NL + p)   * 32];  // prev[p], for enc
  float prev_lane = x[(size_t)(g * NL + l32) * 32];  // prev[l32], for argmax
  float h_reg = 0.f;                                  // own h[p][k], f32 carry

  __syncthreads();

  // hoisted static edge-phase operands (constant across steps)
  h2 wv16[4];
  #pragma unroll
  for (int q = 0; q < 4; ++q) wv16[q] = swea16[cp0 + q];
  const int j0 = 2 * w, j1 = 2 * w + 1;
  h2 ea00, ea01, ea10, ea11;
  {
    f16 e;
    e = (f16)sea[j0 * S3 + m16];      ea00 = (h2){e, e};
    e = (f16)sea[j0 * S3 + 16 + m16]; ea01 = (h2){e, e};
    e = (f16)sea[j1 * S3 + m16];      ea10 = (h2){e, e};
    e = (f16)sea[j1 * S3 + 16 + m16]; ea11 = (h2){e, e};
  }
  const h2 h001 = {(_Float16)0.01f, (_Float16)0.01f};

  // ---- 32 steps ----
  for (int s = 0; s < 32; ++s) {
    // NEG-fill slice of this graph's band (skips diagonal block; overlaps compute)
    {
      const f32x4 nv = {NEGV, NEGV, NEGV, NEGV};
      #pragma unroll
      for (int q = 0; q < 2; ++q) {
        int idx = (s * 2 + q) * NT + t;
        int row = idx >> 11;
        int c4  = idx & 2047;
        if ((c4 >> 3) != g) {
          f32x4* dptr = reinterpret_cast<f32x4*>(out + (size_t)(g * NL + row) * NTOT) + c4;
          __builtin_nontemporal_store(nv, dptr);
        }
      }
    }

    // enc = relu([prev | h] @ W_enc.T)   (own rows)
    float enc_reg;
    {
      float accA = 0.f, accB = 0.f;
      #pragma unroll
      for (int c2 = 0; c2 < 8; ++c2) {
        accA = FDOT2(sWenc16[k * SH + c2],     sh16[p * SH + c2],     accA);
        accB = FDOT2(sWenc16[k * SH + 8 + c2], sh16[p * SH + 8 + c2], accB);
      }
      enc_reg = fmaxf(fmaf(swenc0[k], prev_row, accA + accB), 0.f);
      float en = __shfl_xor(enc_reg, 1);
      if (!(k & 1)) senc16[p * SH + (k >> 1)] = PKRTZ(enc_reg, en);
    }

    // A/B = enc @ W_m1 halves  (own rows)
    {
      float a = 0.f, b = 0.f;
      #pragma unroll
      for (int c2 = 0; c2 < 16; ++c2) {
        h2 ev = senc16[p * SH + c2];
        a = FDOT2(sW1d16[k * SH + c2], ev, a);
        b = FDOT2(sW1s16[k * SH + c2], ev, b);
      }
      float an = __shfl_xor(a, 1);
      float bn = __shfl_xor(b, 1);
      if (!(k & 1)) {
        sA16[p * SH + (k >> 1)] = PKRTZ(a, an);
        sB16[p * SH + (k >> 1)] = PKRTZ(b, bn);
      }
    }
    lds_barrier();   // B1: sB16 (cross-wave) visible

    // edge phase via MFMA (f16): wave w owns dst j0, j1
    {
      const f32x4 zero = {0.f, 0.f, 0.f, 0.f};
      #pragma unroll
      for (int jg = 0; jg < 2; ++jg) {
        const int j = jg ? j1 : j0;
        const h2 eaA = jg ? ea10 : ea00;
        const h2 eaB = jg ? ea11 : ea01;
        F8 a0, a1;
        #pragma unroll
        for (int q = 0; q < 4; ++q) {
          h2 aj = sA16[j * SH + cp0 + q];
          h2 b0 = sB16[m16 * SH + cp0 + q];
          h2 b1 = sB16[(16 + m16) * SH + cp0 + q];
          h2 t0 = aj + __builtin_elementwise_fma(eaA, wv16[q], b0);
          h2 t1 = aj + __builtin_elementwise_fma(eaB, wv16[q], b1);
          a0.h[q] = __builtin_elementwise_max(t0, t0 * h001);   // pk lrelu
          a1.h[q] = __builtin_elementwise_max(t1, t1 * h001);
        }
        f32x4 d00 = __builtin_amdgcn_mfma_f32_16x16x32_f16(a0.v, bf0.v, zero, 0, 0, 0);
        f32x4 d01 = __builtin_amdgcn_mfma_f32_16x16x32_f16(a0.v, bf1.v, zero, 0, 0, 0);
        f32x4 d10 = __builtin_amdgcn_mfma_f32_16x16x32_f16(a1.v, bf0.v, zero, 0, 0, 0);
        f32x4 d11 = __builtin_amdgcn_mfma_f32_16x16x32_f16(a1.v, bf1.v, zero, 0, 0, 0);
        #pragma unroll
        for (int nt = 0; nt < 2; ++nt) {
          f32x4 da = nt ? d01 : d00;
          f32x4 db = nt ? d11 : d10;
          float mv = fmaxf(fmaxf(fmaxf(da[0], da[1]), fmaxf(da[2], da[3])),
                           fmaxf(fmaxf(db[0], db[1]), fmaxf(db[2], db[3])));
          mv = fmaxf(mv, __shfl_xor(mv, 16));
          mv = fmaxf(mv, __shfl_xor(mv, 32));
          if (lane < 16)
            ((f16*)saggr16)[j * 34 + nt * 16 + lane] = (f16)lrelu(mv);
        }
      }
    }

    // u = lrelu([enc | aggr] @ W_u.T) -> sA16 (own rows)
    {
      float accA = 0.f, accB = 0.f;
      #pragma unroll
      for (int c2 = 0; c2 < 16; ++c2) {
        accA = FDOT2(sWu16[k * 33 + c2],      senc16[p * SH + c2],  accA);
        accB = FDOT2(sWu16[k * 33 + 16 + c2], saggr16[p * SH + c2], accB);
      }
      float ur = lrelu(accA + accB);
      float un = __shfl_xor(ur, 1);
      if (!(k & 1)) sA16[p * SH + (k >> 1)] = PKRTZ(ur, un);
    }

    // GRU (own rows) — f16 weights via fdot2, h carry in f32 register
    float hnew;
    {
      float gr = 0.f, gz = 0.f, gn = 0.f, hr = 0.f, hz = 0.f, hn = 0.f;
      #pragma unroll
      for (int c2 = 0; c2 < 16; ++c2) {
        h2 uu = sA16[p * SH + c2];
        h2 hh = sh16[p * SH + c2];
        gr = FDOT2(sWih16[k * SH + c2],        uu, gr);
        gz = FDOT2(sWih16[(32 + k) * SH + c2], uu, gz);
        gn = FDOT2(sWih16[(64 + k) * SH + c2], uu, gn);
        hr = FDOT2(sWhh16[k * SH + c2],        hh, hr);
        hz = FDOT2(sWhh16[(32 + k) * SH + c2], hh, hz);
        hn = FDOT2(sWhh16[(64 + k) * SH + c2], hh, hn);
      }
      float r  = fsigmoid(gr + hr);
      float z  = fsigmoid(gz + hz);
      float nn = ftanh(gn + r * hn);
      hnew = (1.f - z) * nn + z * h_reg;
    }
    h_reg = hnew;
    {
      float hx = __shfl_xor(hnew, 1);
      if (!(k & 1)) sh16[p * SH + (k >> 1)] = PKRTZ(hnew, hx);
    }

    // mst partial from registers
    {
      float part = sWmst[k] * enc_reg + sWmst[32 + k] * hnew;
      #pragma unroll
      for (int mask = 1; mask <= 16; mask <<= 1) part += __shfl_xor(part, mask);
      if (k == 0) smst[p] = part;
    }
    lds_barrier();   // B2: smst all rows visible

    // masked argmax — every wave computes redundantly (identical result)
    {
      float val = (prev_lane > 0.f) ? NEGV : smst[l32];
      int idx = l32;
      #pragma unroll
      for (int mask = 16; mask >= 1; mask >>= 1) {
        float ov = __shfl_xor(val, mask);
        int   oi = __shfl_xor(idx, mask);
        if (ov > val || (ov == val && oi < idx)) { val = ov; idx = oi; }
      }
      if (l32 == idx) prev_lane = 1.0f;
      if (p   == idx) prev_row  = 1.0f;
    }
  }

  // ---- final predictor ----
  {
    const f16* hrow = (const f16*)&sh16[p * SH];
    float c1 = 0.f, c2 = 0.f;
    #pragma unroll
    for (int c = 0; c < 32; ++c) {
      float hc = (float)hrow[c];
      c1 = fmaf(W_p1[k * 65 + c],      hc, c1);
      c2 = fmaf(W_p1[k * 65 + 32 + c], hc, c2);
    }
    sC1[p * S3 + k] = c1;
    sC2[p * S3 + k] = c2;
  }
  lds_barrier();

  // out(src=i, dst=j): i = p, j = k
  {
    const int i = p, j = k;
    float eat = sea[j * S3 + i];
    float acc = 0.f;
    #pragma unroll
    for (int c = 0; c < 32; ++c) {
      float v = sC1[i * S3 + c] + sC2[j * S3 + c] + eat * swp1e[c];
      acc = fmaf(W_p2[c], fmaxf(v, 0.f), acc);
    }
    out[(size_t)(g * NL + i) * NTOT + (g * NL + j)] = acc;
  }
}

extern "C" void kernel_launch(void* const* d_in, const int* in_sizes, int n_in,
                              void* d_out, int out_size, void* d_ws, size_t ws_size,
                              hipStream_t stream) {
  const float* x         = (const float*)d_in[0];
  const float* edge_attr = (const float*)d_in[1];
  const float* W_enc     = (const float*)d_in[2];
  const float* W_m1      = (const float*)d_in[3];
  const float* W_m2      = (const float*)d_in[4];
  const float* W_u       = (const float*)d_in[5];
  const float* W_ih      = (const float*)d_in[6];
  const float* W_hh      = (const float*)d_in[7];
  const float* W_mst     = (const float*)d_in[8];
  const float* W_p1      = (const float*)d_in[9];
  const float* W_p2      = (const float*)d_in[10];
  float* out = (float*)d_out;

  hipLaunchKernelGGL(prims_fused, dim3(NG), dim3(NT), 0, stream,
                     x, edge_attr, W_enc, W_m1, W_m2, W_u, W_ih, W_hh,
                     W_mst, W_p1, W_p2, out);
}

// Round 8
// 214.584 us; speedup vs baseline: 1.6247x; 1.0698x over previous
//
#include <hip/hip_runtime.h>
#include <stdint.h>
#include <math.h>

#define NEGV -1000000000.0f

constexpr int NG   = 256;   // graphs
constexpr int NL   = 32;    // nodes per graph == L == steps
constexpr int NT   = 1024;  // threads per block
constexpr int NTOT = 8192;  // total nodes
constexpr int S3   = 33;    // f32 stride for per-lane-row arrays
constexpr int SH   = 20;    // h2 stride (40 f16, 80B rows, 16B-aligned)
constexpr int SWU  = 36;    // h2 stride for W_u rows (144B, 16B-aligned)

typedef _Float16 f16;
typedef __attribute__((ext_vector_type(2))) _Float16 h2;
typedef __attribute__((ext_vector_type(8))) _Float16 h8;
typedef __attribute__((ext_vector_type(8))) _Float16 f16x8;
typedef __attribute__((ext_vector_type(4))) float f32x4;

union H8 { h8 v; h2 e[4]; };

#if __has_builtin(__builtin_amdgcn_fdot2)
#define FDOT2(a, b, c) __builtin_amdgcn_fdot2((a), (b), (c), false)
#else
__device__ __forceinline__ float FDOT2(h2 a, h2 b, float c) {
  return fmaf((float)a.y, (float)b.y, fmaf((float)a.x, (float)b.x, c));
}
#endif

#if __has_builtin(__builtin_amdgcn_cvt_pkrtz)
__device__ __forceinline__ h2 PKRTZ(float a, float b) {
  return __builtin_bit_cast(h2, __builtin_amdgcn_cvt_pkrtz(a, b));
}
#else
__device__ __forceinline__ h2 PKRTZ(float a, float b) {
  return (h2){(_Float16)a, (_Float16)b};
}
#endif

__device__ __forceinline__ h2 mkh2(float a, float b) {   // RNE pack (staging only)
  return (h2){(_Float16)a, (_Float16)b};
}

__device__ __forceinline__ H8 ld8(const h2* p) {
  H8 r; r.v = *(const h8*)__builtin_assume_aligned(p, 16); return r;
}
__device__ __forceinline__ float dot8(const H8& a, const H8& b, float acc) {
  acc = FDOT2(a.e[0], b.e[0], acc);
  acc = FDOT2(a.e[1], b.e[1], acc);
  acc = FDOT2(a.e[2], b.e[2], acc);
  acc = FDOT2(a.e[3], b.e[3], acc);
  return acc;
}

__device__ __forceinline__ float lrelu(float v) { return fmaxf(v, 0.01f * v); }

__device__ __forceinline__ void lds_barrier() {
  asm volatile("s_waitcnt lgkmcnt(0)" ::: "memory");
  __builtin_amdgcn_sched_barrier(0);
  __builtin_amdgcn_s_barrier();
  __builtin_amdgcn_sched_barrier(0);
}

__device__ __forceinline__ float fsigmoid(float x) {
  return __builtin_amdgcn_rcpf(1.f + __expf(-x));
}
__device__ __forceinline__ float ftanh(float x) {
  x = fminf(fmaxf(x, -15.f), 15.f);
  float e = __expf(2.f * x);
  return (e - 1.f) * __builtin_amdgcn_rcpf(e + 1.f);
}

__global__ __launch_bounds__(NT, 4) void prims_fused(
    const float* __restrict__ x, const float* __restrict__ edge_attr,
    const float* __restrict__ W_enc, const float* __restrict__ W_m1,
    const float* __restrict__ W_m2, const float* __restrict__ W_u,
    const float* __restrict__ W_ih, const float* __restrict__ W_hh,
    const float* __restrict__ W_mst, const float* __restrict__ W_p1,
    const float* __restrict__ W_p2, float* __restrict__ out)
{
  // packed f16x2 state, stride SH=20 h2 (80B rows, b128-friendly)
  __shared__ __align__(16) h2 sh16[NL * SH];     // hidden state h
  __shared__ __align__(16) h2 senc16[NL * SH];   // enc
  __shared__ __align__(16) h2 sA16[NL * SH];     // msg dst-part; then u
  __shared__ __align__(16) h2 sB16[NL * SH];     // msg src-part
  __shared__ __align__(16) h2 saggr16[NL * SH];  // segment max
  // packed f16x2 weights
  __shared__ __align__(16) h2 sWenc16[NL * SH];  // W_enc[:,1:33]
  __shared__ __align__(16) h2 sW1d16[NL * SH];   // W_m1[:, 0:32]
  __shared__ __align__(16) h2 sW1s16[NL * SH];   // W_m1[:,32:64]
  __shared__ __align__(16) h2 sWu16[NL * SWU];   // W_u rows (32 h2 data + pad)
  __shared__ __align__(16) h2 sWih16[96 * SH];   // W_ih
  __shared__ __align__(16) h2 sWhh16[96 * SH];   // W_hh
  __shared__ h2 swea16[16];                      // W_m1[:,64] pairs
  // f32 oddments
  __shared__ float sea[NL * S3];   // sea[j*S3 + i] = ea(src i, dst j)
  __shared__ float smst[NL];
  __shared__ float swenc0[NL];
  __shared__ float sWmst[2 * NL];
  __shared__ float swp1e[NL];      // W_p1[:,64]
  __shared__ float sC1[NL * S3];   // final predictor src-part
  __shared__ float sC2[NL * S3];   // final predictor dst-part

  const int t    = threadIdx.x;
  const int g    = blockIdx.x;
  const int p    = t >> 5;   // node row
  const int k    = t & 31;   // feature col
  const int w    = t >> 6;   // wave id (16)
  const int lane = t & 63;
  const int l32  = lane & 31;
  const int m16  = lane & 15;
  const int c0   = (lane >> 4) * 8;   // MFMA k-chunk base (f16 elems)
  const int cp0  = (lane >> 4) * 4;   // same in half2 units

  // ---- W_m2^T B-fragments (f16, resident in registers) ----
  union F8 { h2 h[4]; f16x8 v; };
  F8 bf0, bf1;
  #pragma unroll
  for (int q = 0; q < 4; ++q) {
    bf0.h[q] = mkh2(W_m2[m16 * 32 + c0 + 2 * q],        W_m2[m16 * 32 + c0 + 2 * q + 1]);
    bf1.h[q] = mkh2(W_m2[(16 + m16) * 32 + c0 + 2 * q], W_m2[(16 + m16) * 32 + c0 + 2 * q + 1]);
  }

  // ---- one-time staging ----
  for (int idx = t; idx < NL * 16; idx += NT) {
    int r = idx >> 4, c2 = idx & 15;
    sWenc16[r * SH + c2] = mkh2(W_enc[r * 33 + 1 + 2 * c2], W_enc[r * 33 + 2 + 2 * c2]);
    sW1d16[r * SH + c2] = mkh2(W_m1[r * 65 + 2 * c2],      W_m1[r * 65 + 2 * c2 + 1]);
    sW1s16[r * SH + c2] = mkh2(W_m1[r * 65 + 32 + 2 * c2], W_m1[r * 65 + 33 + 2 * c2]);
  }
  for (int idx = t; idx < NL * 32; idx += NT) {
    int r = idx >> 5, c2 = idx & 31;
    sWu16[r * SWU + c2] = mkh2(W_u[r * 64 + 2 * c2], W_u[r * 64 + 2 * c2 + 1]);
  }
  for (int idx = t; idx < 96 * 16; idx += NT) {
    int q = idx >> 4, c2 = idx & 15;
    sWih16[q * SH + c2] = mkh2(W_ih[q * 32 + 2 * c2], W_ih[q * 32 + 2 * c2 + 1]);
    sWhh16[q * SH + c2] = mkh2(W_hh[q * 32 + 2 * c2], W_hh[q * 32 + 2 * c2 + 1]);
  }
  if (t < 16) swea16[t] = mkh2(W_m1[(2 * t) * 65 + 64], W_m1[(2 * t + 1) * 65 + 64]);
  if (t < NL) { swenc0[t] = W_enc[t * 33]; swp1e[t] = W_p1[t * 65 + 64]; }
  if (t < 2 * NL) sWmst[t] = W_mst[t];
  {
    int i = t >> 5, j = t & 31;           // edge t = i*32+j (src i, dst j)
    sea[j * S3 + i] = edge_attr[g * 1024 + t];
  }
  for (int idx = t; idx < NL * SH; idx += NT) sh16[idx] = (h2){(_Float16)0.f, (_Float16)0.f};

  float prev_row  = x[(size_t)(g * NL + p)   * 32];  // prev[p], for enc
  float prev_lane = x[(size_t)(g * NL + l32) * 32];  // prev[l32], for argmax
  float h_reg = 0.f;                                  // own h[p][k], f32 carry

  __syncthreads();

  // hoisted static edge-phase operands
  h2 wv16[4];
  #pragma unroll
  for (int q = 0; q < 4; ++q) wv16[q] = swea16[cp0 + q];
  const int j0 = 2 * w, j1 = 2 * w + 1;
  h2 ea00, ea01, ea10, ea11;
  {
    f16 e;
    e = (f16)sea[j0 * S3 + m16];      ea00 = (h2){e, e};
    e = (f16)sea[j0 * S3 + 16 + m16]; ea01 = (h2){e, e};
    e = (f16)sea[j1 * S3 + m16];      ea10 = (h2){e, e};
    e = (f16)sea[j1 * S3 + 16 + m16]; ea11 = (h2){e, e};
  }
  const h2 h001 = {(_Float16)0.01f, (_Float16)0.01f};

  // ---- 32 steps ----
  for (int s = 0; s < 32; ++s) {
    // NEG-fill slice of this graph's band (skips diagonal block)
    {
      const f32x4 nv = {NEGV, NEGV, NEGV, NEGV};
      #pragma unroll
      for (int q = 0; q < 2; ++q) {
        int idx = (s * 2 + q) * NT + t;
        int row = idx >> 11;
        int c4  = idx & 2047;
        if ((c4 >> 3) != g) {
          f32x4* dptr = reinterpret_cast<f32x4*>(out + (size_t)(g * NL + row) * NTOT) + c4;
          __builtin_nontemporal_store(nv, dptr);
        }
      }
    }

    // h row p in registers (reused by GRU below; sh16 rewritten only after GRU)
    H8 hp0 = ld8(&sh16[p * SH + 0]),  hp1 = ld8(&sh16[p * SH + 4]);
    H8 hp2 = ld8(&sh16[p * SH + 8]),  hp3 = ld8(&sh16[p * SH + 12]);

    // enc = relu([prev | h] @ W_enc.T)   (own rows)
    float enc_reg;
    {
      H8 w0 = ld8(&sWenc16[k * SH + 0]), w1 = ld8(&sWenc16[k * SH + 4]);
      H8 w2 = ld8(&sWenc16[k * SH + 8]), w3 = ld8(&sWenc16[k * SH + 12]);
      float accA = dot8(w1, hp1, dot8(w0, hp0, 0.f));
      float accB = dot8(w3, hp3, dot8(w2, hp2, 0.f));
      enc_reg = fmaxf(fmaf(swenc0[k], prev_row, accA + accB), 0.f);
      float en = __shfl_xor(enc_reg, 1);
      if (!(k & 1)) senc16[p * SH + (k >> 1)] = PKRTZ(enc_reg, en);
    }

    // enc row p in registers (reused by u-phase)
    H8 e0 = ld8(&senc16[p * SH + 0]),  e1 = ld8(&senc16[p * SH + 4]);
    H8 e2 = ld8(&senc16[p * SH + 8]),  e3 = ld8(&senc16[p * SH + 12]);

    // A/B = enc @ W_m1 halves  (own rows)
    {
      H8 d0 = ld8(&sW1d16[k * SH + 0]), d1 = ld8(&sW1d16[k * SH + 4]);
      H8 d2 = ld8(&sW1d16[k * SH + 8]), d3 = ld8(&sW1d16[k * SH + 12]);
      float aA = dot8(d1, e1, dot8(d0, e0, 0.f));
      float aB = dot8(d3, e3, dot8(d2, e2, 0.f));
      H8 s0 = ld8(&sW1s16[k * SH + 0]), s1 = ld8(&sW1s16[k * SH + 4]);
      H8 s2 = ld8(&sW1s16[k * SH + 8]), s3 = ld8(&sW1s16[k * SH + 12]);
      float bA = dot8(s1, e1, dot8(s0, e0, 0.f));
      float bB = dot8(s3, e3, dot8(s2, e2, 0.f));
      float a = aA + aB, b = bA + bB;
      float an = __shfl_xor(a, 1);
      float bn = __shfl_xor(b, 1);
      if (!(k & 1)) {
        sA16[p * SH + (k >> 1)] = PKRTZ(a, an);
        sB16[p * SH + (k >> 1)] = PKRTZ(b, bn);
      }
    }
    lds_barrier();   // B1: sB16 (cross-wave) visible

    // edge phase via MFMA (f16): wave w owns dst j0, j1
    {
      const f32x4 zero = {0.f, 0.f, 0.f, 0.f};
      #pragma unroll
      for (int jg = 0; jg < 2; ++jg) {
        const int j = jg ? j1 : j0;
        const h2 eaA = jg ? ea10 : ea00;
        const h2 eaB = jg ? ea11 : ea01;
        H8 aj = ld8(&sA16[j * SH + cp0]);
        H8 b0 = ld8(&sB16[m16 * SH + cp0]);
        H8 b1 = ld8(&sB16[(16 + m16) * SH + cp0]);
        F8 a0, a1;
        #pragma unroll
        for (int q = 0; q < 4; ++q) {
          h2 t0 = aj.e[q] + __builtin_elementwise_fma(eaA, wv16[q], b0.e[q]);
          h2 t1 = aj.e[q] + __builtin_elementwise_fma(eaB, wv16[q], b1.e[q]);
          a0.h[q] = __builtin_elementwise_max(t0, t0 * h001);   // pk lrelu
          a1.h[q] = __builtin_elementwise_max(t1, t1 * h001);
        }
        f32x4 d00 = __builtin_amdgcn_mfma_f32_16x16x32_f16(a0.v, bf0.v, zero, 0, 0, 0);
        f32x4 d01 = __builtin_amdgcn_mfma_f32_16x16x32_f16(a0.v, bf1.v, zero, 0, 0, 0);
        f32x4 d10 = __builtin_amdgcn_mfma_f32_16x16x32_f16(a1.v, bf0.v, zero, 0, 0, 0);
        f32x4 d11 = __builtin_amdgcn_mfma_f32_16x16x32_f16(a1.v, bf1.v, zero, 0, 0, 0);
        #pragma unroll
        for (int nt = 0; nt < 2; ++nt) {
          f32x4 da = nt ? d01 : d00;
          f32x4 db = nt ? d11 : d10;
          float mv = fmaxf(fmaxf(fmaxf(da[0], da[1]), fmaxf(da[2], da[3])),
                           fmaxf(fmaxf(db[0], db[1]), fmaxf(db[2], db[3])));
          mv = fmaxf(mv, __shfl_xor(mv, 16));
          mv = fmaxf(mv, __shfl_xor(mv, 32));
          if (lane < 16)
            ((f16*)saggr16)[j * (2 * SH) + nt * 16 + lane] = (f16)lrelu(mv);
        }
      }
    }

    // u = lrelu([enc | aggr] @ W_u.T) -> sA16 (own rows; enc rows reused from regs)
    {
      H8 g0 = ld8(&saggr16[p * SH + 0]),  g1 = ld8(&saggr16[p * SH + 4]);
      H8 g2 = ld8(&saggr16[p * SH + 8]),  g3 = ld8(&saggr16[p * SH + 12]);
      H8 u0 = ld8(&sWu16[k * SWU + 0]),  u1 = ld8(&sWu16[k * SWU + 4]);
      H8 u2 = ld8(&sWu16[k * SWU + 8]),  u3 = ld8(&sWu16[k * SWU + 12]);
      H8 u4 = ld8(&sWu16[k * SWU + 16]), u5 = ld8(&sWu16[k * SWU + 20]);
      H8 u6 = ld8(&sWu16[k * SWU + 24]), u7 = ld8(&sWu16[k * SWU + 28]);
      float aA = dot8(u1, e1, dot8(u0, e0, 0.f));
      float aB = dot8(u3, e3, dot8(u2, e2, 0.f));
      float aC = dot8(u5, g1, dot8(u4, g0, 0.f));
      float aD = dot8(u7, g3, dot8(u6, g2, 0.f));
      float ur = lrelu((aA + aB) + (aC + aD));
      float un = __shfl_xor(ur, 1);
      if (!(k & 1)) sA16[p * SH + (k >> 1)] = PKRTZ(ur, un);
    }

    // GRU (own rows) — b128 weight rows, h rows reused from regs
    float hnew;
    {
      H8 U0 = ld8(&sA16[p * SH + 0]),  U1 = ld8(&sA16[p * SH + 4]);
      H8 U2 = ld8(&sA16[p * SH + 8]),  U3 = ld8(&sA16[p * SH + 12]);
      float gr, gz, gn, hr, hz, hn;
      {
        H8 w0 = ld8(&sWih16[k * SH + 0]), w1 = ld8(&sWih16[k * SH + 4]);
        H8 w2 = ld8(&sWih16[k * SH + 8]), w3 = ld8(&sWih16[k * SH + 12]);
        gr = dot8(w3, U3, dot8(w2, U2, dot8(w1, U1, dot8(w0, U0, 0.f))));
      }
      {
        H8 w0 = ld8(&sWih16[(32 + k) * SH + 0]), w1 = ld8(&sWih16[(32 + k) * SH + 4]);
        H8 w2 = ld8(&sWih16[(32 + k) * SH + 8]), w3 = ld8(&sWih16[(32 + k) * SH + 12]);
        gz = dot8(w3, U3, dot8(w2, U2, dot8(w1, U1, dot8(w0, U0, 0.f))));
      }
      {
        H8 w0 = ld8(&sWih16[(64 + k) * SH + 0]), w1 = ld8(&sWih16[(64 + k) * SH + 4]);
        H8 w2 = ld8(&sWih16[(64 + k) * SH + 8]), w3 = ld8(&sWih16[(64 + k) * SH + 12]);
        gn = dot8(w3, U3, dot8(w2, U2, dot8(w1, U1, dot8(w0, U0, 0.f))));
      }
      {
        H8 w0 = ld8(&sWhh16[k * SH + 0]), w1 = ld8(&sWhh16[k * SH + 4]);
        H8 w2 = ld8(&sWhh16[k * SH + 8]), w3 = ld8(&sWhh16[k * SH + 12]);
        hr = dot8(w3, hp3, dot8(w2, hp2, dot8(w1, hp1, dot8(w0, hp0, 0.f))));
      }
      {
        H8 w0 = ld8(&sWhh16[(32 + k) * SH + 0]), w1 = ld8(&sWhh16[(32 + k) * SH + 4]);
        H8 w2 = ld8(&sWhh16[(32 + k) * SH + 8]), w3 = ld8(&sWhh16[(32 + k) * SH + 12]);
        hz = dot8(w3, hp3, dot8(w2, hp2, dot8(w1, hp1, dot8(w0, hp0, 0.f))));
      }
      {
        H8 w0 = ld8(&sWhh16[(64 + k) * SH + 0]), w1 = ld8(&sWhh16[(64 + k) * SH + 4]);
        H8 w2 = ld8(&sWhh16[(64 + k) * SH + 8]), w3 = ld8(&sWhh16[(64 + k) * SH + 12]);
        hn = dot8(w3, hp3, dot8(w2, hp2, dot8(w1, hp1, dot8(w0, hp0, 0.f))));
      }
      float r  = fsigmoid(gr + hr);
      float z  = fsigmoid(gz + hz);
      float nn = ftanh(gn + r * hn);
      hnew = (1.f - z) * nn + z * h_reg;
    }
    h_reg = hnew;
    {
      float hx = __shfl_xor(hnew, 1);
      if (!(k & 1)) sh16[p * SH + (k >> 1)] = PKRTZ(hnew, hx);
    }

    // mst partial from registers
    {
      float part = sWmst[k] * enc_reg + sWmst[32 + k] * hnew;
      #pragma unroll
      for (int mask = 1; mask <= 16; mask <<= 1) part += __shfl_xor(part, mask);
      if (k == 0) smst[p] = part;
    }
    lds_barrier();   // B2: smst all rows visible

    // masked argmax — every wave computes redundantly (identical result)
    {
      float val = (prev_lane > 0.f) ? NEGV : smst[l32];
      int idx = l32;
      #pragma unroll
      for (int mask = 16; mask >= 1; mask >>= 1) {
        float ov = __shfl_xor(val, mask);
        int   oi = __shfl_xor(idx, mask);
        if (ov > val || (ov == val && oi < idx)) { val = ov; idx = oi; }
      }
      if (l32 == idx) prev_lane = 1.0f;
      if (p   == idx) prev_row  = 1.0f;
    }
  }

  // ---- final predictor ----
  {
    const f16* hrow = (const f16*)&sh16[p * SH];
    float c1 = 0.f, c2 = 0.f;
    #pragma unroll
    for (int c = 0; c < 32; ++c) {
      float hc = (float)hrow[c];
      c1 = fmaf(W_p1[k * 65 + c],      hc, c1);
      c2 = fmaf(W_p1[k * 65 + 32 + c], hc, c2);
    }
    sC1[p * S3 + k] = c1;
    sC2[p * S3 + k] = c2;
  }
  lds_barrier();

  // out(src=i, dst=j): i = p, j = k
  {
    const int i = p, j = k;
    float eat = sea[j * S3 + i];
    float acc = 0.f;
    #pragma unroll
    for (int c = 0; c < 32; ++c) {
      float v = sC1[i * S3 + c] + sC2[j * S3 + c] + eat * swp1e[c];
      acc = fmaf(W_p2[c], fmaxf(v, 0.f), acc);
    }
    out[(size_t)(g * NL + i) * NTOT + (g * NL + j)] = acc;
  }
}

extern "C" void kernel_launch(void* const* d_in, const int* in_sizes, int n_in,
                              void* d_out, int out_size, void* d_ws, size_t ws_size,
                              hipStream_t stream) {
  const float* x         = (const float*)d_in[0];
  const float* edge_attr = (const float*)d_in[1];
  const float* W_enc     = (const float*)d_in[2];
  const float* W_m1      = (const float*)d_in[3];
  const float* W_m2      = (const float*)d_in[4];
  const float* W_u       = (const float*)d_in[5];
  const float* W_ih      = (const float*)d_in[6];
  const float* W_hh      = (const float*)d_in[7];
  const float* W_mst     = (const float*)d_in[8];
  const float* W_p1      = (const float*)d_in[9];
  const float* W_p2      = (const float*)d_in[10];
  float* out = (float*)d_out;

  hipLaunchKernelGGL(prims_fused, dim3(NG), dim3(NT), 0, stream,
                     x, edge_attr, W_enc, W_m1, W_m2, W_u, W_ih, W_hh,
                     W_mst, W_p1, W_p2, out);
}